// Round 6
// baseline (1281.888 us; speedup 1.0000x reference)
//
#include <hip/hip_runtime.h>
#include <hip/hip_bf16.h>
#include <math.h>

// Problem constants
#define Bsz  4
#define Nseq 2048
#define Cdim 1024
#define Hn   16
#define HDd  64
#define MTt  40
#define HIDd 4096

typedef __attribute__((ext_vector_type(8))) short  short8;
typedef __attribute__((ext_vector_type(4))) float  floatx4;

__device__ __forceinline__ floatx4 mfma16(short8 a, short8 b, floatx4 c) {
    return __builtin_amdgcn_mfma_f32_16x16x32_bf16(a, b, c, 0, 0, 0);
}

// async global->LDS, 16B per lane; LDS dest must be wave-uniform base + lane*16
__device__ __forceinline__ void load_lds16(const void* g, void* l) {
    __builtin_amdgcn_global_load_lds(
        (__attribute__((address_space(1))) void*)(g),
        (__attribute__((address_space(3))) void*)(l),
        16, 0, 0);
}

__device__ __forceinline__ unsigned short f2bu(float f) {
    union { __hip_bfloat16 h; unsigned short u; } cv;
    cv.h = __float2bfloat16(f);
    return cv.u;
}

template<int MAP>
__device__ __forceinline__ int rowmap(int r) {
    if constexpr (MAP == 1) {          // token rows: r in [0,160) -> b*N + n, n<MT
        int b = r / MTt; return b * Nseq + (r - b * MTt);
    } else if constexpr (MAP == 2) {   // image rows: r in [0,8032) -> b*N + MT + n
        int b = r / (Nseq - MTt); return b * Nseq + MTt + (r - b * (Nseq - MTt));
    } else {
        return r;
    }
}

// ---------------------------------------------------------------------------
// 128x128 tile GEMM, BK=64, C = A[M,K] * Bw[N,K]^T (+bias, epilogues)
// EPI: 0 = QKV scatter (q*scale, k, v^T)   1 = proj (+g1 residual, fp32 out)
//      2 = FC1 + exact gelu (bf16 out)     3 = FC2 (+g2 residual scatter, fp32)
// ---------------------------------------------------------------------------
template<int EPI, int AMAP, int CMAP>
__global__ __launch_bounds__(256, 3)
void gemm128(const unsigned short* __restrict__ A,
             const unsigned short* __restrict__ Bw,
             int M, int K,
             const float* __restrict__ bias,
             const float* __restrict__ bias2,
             const float* __restrict__ gamma,
             const float* __restrict__ resid,
             float* __restrict__ outf,
             unsigned short* __restrict__ outh,
             unsigned short* __restrict__ q_out,
             unsigned short* __restrict__ k_out,
             unsigned short* __restrict__ vt_out,
             int out_row_off)
{
    __shared__ unsigned short As[128 * 64];
    __shared__ unsigned short Bs[128 * 64];

    const int t    = threadIdx.x;
    const int lane = t & 63;
    const int quad = lane >> 4, lcol = lane & 15;
    const int wid  = t >> 6;
    const int wm   = wid >> 1, wn = wid & 1;
    const int m0   = blockIdx.y * 128;
    const int n0   = blockIdx.x * 128;

    floatx4 zero4 = {0.f, 0.f, 0.f, 0.f};
    floatx4 acc[4][4];
#pragma unroll
    for (int i = 0; i < 4; ++i)
#pragma unroll
        for (int j = 0; j < 4; ++j) acc[i][j] = zero4;

    const int c8 = (t & 7) << 3;            // element col within 64-wide K slab
    const unsigned short* aga[4];
    const unsigned short* bga[4];
#pragma unroll
    for (int i = 0; i < 4; ++i) {
        int lr = m0 + i * 32 + (t >> 3);
        if (lr > M - 1) lr = M - 1;
        int sr = rowmap<AMAP>(lr);
        aga[i] = A  + (size_t)sr * K + c8;
        bga[i] = Bw + (size_t)(n0 + i * 32 + (t >> 3)) * K + c8;
    }

    const int nkt = K >> 6;
    for (int kt = 0; kt < nkt; ++kt) {
        const int k0 = kt << 6;
        __syncthreads();
#pragma unroll
        for (int i = 0; i < 4; ++i)
            load_lds16(aga[i] + k0, (unsigned short*)As + i * 2048 + t * 8);
#pragma unroll
        for (int i = 0; i < 4; ++i)
            load_lds16(bga[i] + k0, (unsigned short*)Bs + i * 2048 + t * 8);
        __syncthreads();

#pragma unroll
        for (int kk = 0; kk < 2; ++kk) {
            short8 af[4], bfr[4];
#pragma unroll
            for (int i = 0; i < 4; ++i)
                af[i] = *(const short8*)(As + (wm * 64 + i * 16 + lcol) * 64 + kk * 32 + quad * 8);
#pragma unroll
            for (int j = 0; j < 4; ++j)
                bfr[j] = *(const short8*)(Bs + (wn * 64 + j * 16 + lcol) * 64 + kk * 32 + quad * 8);
#pragma unroll
            for (int i = 0; i < 4; ++i)
#pragma unroll
                for (int j = 0; j < 4; ++j)
                    acc[i][j] = mfma16(af[i], bfr[j], acc[i][j]);
        }
    }

    // epilogue; C/D layout: col = lane&15, row = quad*4 + reg  [m89-verified]
    const int rb = m0 + wm * 64 + quad * 4;
    const int cb = n0 + wn * 64 + lcol;
#pragma unroll
    for (int i = 0; i < 4; ++i) {
#pragma unroll
        for (int j = 0; j < 4; ++j) {
            const int c = cb + j * 16;
#pragma unroll
            for (int rg = 0; rg < 4; ++rg) {
                const int r = rb + i * 16 + rg;
                if (r >= M) continue;
                float v = acc[i][j][rg];
                if constexpr (EPI == 0) {
                    int b = r >> 11, n = r & (Nseq - 1);
                    if (c < Cdim) {
                        float qv = (v + bias[c]) * 0.125f;    // (h@W^T + q_bias)*scale
                        int hh = c >> 6, d = c & 63;
                        q_out[(((size_t)b * Hn + hh) * Nseq + n) * HDd + d] = f2bu(qv);
                    } else if (c < 2 * Cdim) {
                        int cc = c - Cdim; int hh = cc >> 6, d = cc & 63;
                        k_out[(((size_t)b * Hn + hh) * Nseq + n) * HDd + d] = f2bu(v);
                    } else {
                        int cc = c - 2 * Cdim; int hh = cc >> 6, d = cc & 63;
                        vt_out[(((size_t)b * Hn + hh) * HDd + d) * Nseq + n] = f2bu(v + bias2[cc]);
                    }
                } else if constexpr (EPI == 1) {
                    size_t idx = (size_t)r * Cdim + c;
                    outf[idx] = resid[idx] + gamma[c] * (v + bias[c]);
                } else if constexpr (EPI == 2) {
                    float xg = v + bias[c];
                    float ge = 0.5f * xg * (1.f + erff(xg * 0.70710678118654752f));
                    outh[(size_t)(r + out_row_off) * HIDd + c] = f2bu(ge);
                } else {
                    int sr = rowmap<CMAP>(r);
                    size_t idx = (size_t)sr * Cdim + c;
                    outf[idx] = resid[idx] + gamma[c] * (v + bias[c]);
                }
            }
        }
    }
}

// ---------------------------------------------------------------------------
// Flash attention v6: round-2 config (229 us) + NON-TEMPORAL bias loads.
//  - Theory: attn is fetch-bound; excess fetch (~280 MB over unique) is K/V
//    re-read across the 16 qt-reuses, evicted from L3 by the 268 MB fp32
//    bias stream. nt-marking the bias loads keeps K/V (32 MB) L3-resident.
//  - NO XCD swizzle, launch_bounds(256,3): r2-vs-r4 A/B showed higher
//    concurrency thrashes L3 (fetch 600->1016 MB). Keep ~2 blocks/CU.
//  - Bias loaded directly in MFMA C-layout into registers (coalesced 64B
//    runs per quad-row); no EB LDS region.
//  - Ps/Vs stride-72 (non-pow-2): softmax u16 writes and PV b128 reads
//    are <=2-way (free).  V register-staged (DMA can't pad - m104/m108).
//  - No max subtraction (scores bounded); row sums via MFMA ones-column.
//  - Ps aliases Qs (Q frags in regs; lgkm drained at first barrier).
// LDS: Ps 128x72 (>=Qs 128x64) | Ks 64x64 | Vs 64x72 = 35,840 B
// grid: 1024 blocks (b,h,qt); block 256 = 4 waves x 32 q-rows.
// ---------------------------------------------------------------------------
__global__ __launch_bounds__(256, 3)
void attn_kernel(const unsigned short* __restrict__ q,
                 const unsigned short* __restrict__ k,
                 const unsigned short* __restrict__ vt,
                 const float* __restrict__ bias,
                 const int* __restrict__ mask,
                 unsigned short* __restrict__ attn_o)
{
    __shared__ unsigned short lds[17920];
    unsigned short* PS = lds;            // 128 x 72   [0, 9216)   (Qs 128x64 alias)
    unsigned short* KS = lds + 9216;     // 64 keys x 64d [9216, 13312)
    unsigned short* VS = lds + 13312;    // 64 d x 72  [13312, 17920)

    const int t    = threadIdx.x;
    const int lane = t & 63, wid = t >> 6;
    const int quad = lane >> 4, lcol = lane & 15;

    const int b  = blockIdx.x & 3;
    const int hq = blockIdx.x >> 2;
    const int h  = hq & 15;
    const int qt = hq >> 4;

    const size_t bh = (size_t)b * Hn + h;
    const unsigned short* qbase = q  + (bh * Nseq + qt * 128) * HDd;
    const unsigned short* kbase = k  + bh * Nseq * HDd;
    const unsigned short* vbase = vt + bh * HDd * Nseq;
    const float* bbase = bias + ((size_t)h * Nseq + qt * 128) * Nseq;

    // Q -> LDS (PS region, stride 64), read frags, then PS is reusable
#pragma unroll
    for (int i = 0; i < 4; ++i)
        load_lds16(qbase + i * 2048 + t * 8, (unsigned short*)PS + i * 2048 + t * 8);
    __syncthreads();

    short8 aq[2][2];
#pragma unroll
    for (int mt = 0; mt < 2; ++mt)
#pragma unroll
        for (int kk = 0; kk < 2; ++kk)
            aq[mt][kk] = *(const short8*)(PS + (wid * 32 + mt * 16 + lcol) * 64 + kk * 32 + quad * 8);

    short8 ones8;
#pragma unroll
    for (int i = 0; i < 8; ++i) ones8[i] = (short)0x3F80;   // bf16 1.0

    floatx4 zero4 = {0.f, 0.f, 0.f, 0.f};
    floatx4 o[2][4], osum[2];
#pragma unroll
    for (int mt = 0; mt < 2; ++mt) {
        osum[mt] = zero4;
#pragma unroll
        for (int dj = 0; dj < 4; ++dj) o[mt][dj] = zero4;
    }

    const int tr = t >> 3;            // 0..31
    const int tc = (t & 7) << 3;      // 0..56

    for (int kt = 0; kt < 32; ++kt) {
        __syncthreads();   // prev tile's PS/VS consumers done; frag lgkm drained (kt=0)

        // ---- staging: issue all global reads first ----
        const unsigned short* kb = kbase + kt * 4096;
        load_lds16(kb + t * 8,        KS + t * 8);
        load_lds16(kb + 2048 + t * 8, KS + 2048 + t * 8);

        short8 vreg[2];
#pragma unroll
        for (int i = 0; i < 2; ++i)
            vreg[i] = *(const short8*)(vbase + (size_t)(i * 32 + tr) * Nseq + kt * 64 + tc);

        // bias directly in MFMA C-layout, NON-TEMPORAL (single-use stream;
        // keep it from evicting the K/V working set out of L3):
        // row = wid*32+mt*16+quad*4+rg, col = kt*64 + j*16 + lcol
        float breg[2][4][4];
#pragma unroll
        for (int mt = 0; mt < 2; ++mt)
#pragma unroll
            for (int rg = 0; rg < 4; ++rg) {
                const float* bp = bbase
                    + (size_t)(wid * 32 + mt * 16 + quad * 4 + rg) * Nseq
                    + kt * 64;
#pragma unroll
                for (int j = 0; j < 4; ++j)
                    breg[mt][rg][j] = __builtin_nontemporal_load(bp + j * 16 + lcol);
            }

        int mk[4];
#pragma unroll
        for (int j = 0; j < 4; ++j)
            mk[j] = mask[b * Nseq + kt * 64 + j * 16 + lcol];

        // ---- LDS writes (padded stride 72) ----
#pragma unroll
        for (int i = 0; i < 2; ++i)
            *(short8*)(VS + (i * 32 + tr) * 72 + tc) = vreg[i];
        __syncthreads();   // K DMA + V lds writes visible

        // ---- S = Q K^T ----
        floatx4 s[2][4];
#pragma unroll
        for (int mt = 0; mt < 2; ++mt)
#pragma unroll
            for (int j = 0; j < 4; ++j) s[mt][j] = zero4;
#pragma unroll
        for (int kk = 0; kk < 2; ++kk) {
#pragma unroll
            for (int j = 0; j < 4; ++j) {
                short8 bk = *(const short8*)(KS + (j * 16 + lcol) * 64 + kk * 32 + quad * 8);
                s[0][j] = mfma16(aq[0][kk], bk, s[0][j]);
                s[1][j] = mfma16(aq[1][kk], bk, s[1][j]);
            }
        }

        // ---- softmax numerators (exp(s+bias), masked), write P (C-layout rows) ----
#pragma unroll
        for (int mt = 0; mt < 2; ++mt) {
#pragma unroll
            for (int rg = 0; rg < 4; ++rg) {
                const int prow = wid * 32 + mt * 16 + quad * 4 + rg;
#pragma unroll
                for (int j = 0; j < 4; ++j) {
                    float p = __expf(s[mt][j][rg] + breg[mt][rg][j]);
                    p = mk[j] ? p : 0.f;
                    PS[prow * 72 + j * 16 + lcol] = f2bu(p);
                }
            }
        }

        // ---- O += P V  (+ row-sum via ones column); own-wave rows, no barrier ----
#pragma unroll
        for (int kk2 = 0; kk2 < 2; ++kk2) {
            short8 ap[2], bv[4];
#pragma unroll
            for (int mt = 0; mt < 2; ++mt)
                ap[mt] = *(const short8*)(PS + (wid * 32 + mt * 16 + lcol) * 72 + kk2 * 32 + quad * 8);
#pragma unroll
            for (int dj = 0; dj < 4; ++dj)
                bv[dj] = *(const short8*)(VS + (dj * 16 + lcol) * 72 + kk2 * 32 + quad * 8);
#pragma unroll
            for (int mt = 0; mt < 2; ++mt) {
#pragma unroll
                for (int dj = 0; dj < 4; ++dj)
                    o[mt][dj] = mfma16(ap[mt], bv[dj], o[mt][dj]);
                osum[mt] = mfma16(ap[mt], ones8, osum[mt]);
            }
        }
    }

    // ---- normalize by MFMA row sums, store ----
#pragma unroll
    for (int mt = 0; mt < 2; ++mt) {
#pragma unroll
        for (int rg = 0; rg < 4; ++rg) {
            const float inv = 1.f / osum[mt][rg];
            const int rq = qt * 128 + wid * 32 + mt * 16 + quad * 4 + rg;
#pragma unroll
            for (int dj = 0; dj < 4; ++dj) {
                const int c = h * HDd + dj * 16 + lcol;
                attn_o[((size_t)b * Nseq + rq) * Cdim + c] = f2bu(o[mt][dj][rg] * inv);
            }
        }
    }
}

// ---------------------------------------------------------------------------
// LayerNorm over C=1024, one block per token. sel=1: pick (w1,b1) if n<MT else (w2,b2)
// ---------------------------------------------------------------------------
__global__ __launch_bounds__(256)
void ln_kernel(const float* __restrict__ x,
               unsigned short* __restrict__ out,
               const float* __restrict__ w1, const float* __restrict__ b1,
               const float* __restrict__ w2, const float* __restrict__ b2,
               int sel)
{
    __shared__ float red[8];
    const int r = blockIdx.x, t = threadIdx.x;
    const float4 v = ((const float4*)(x + (size_t)r * Cdim))[t];
    float s1 = v.x + v.y + v.z + v.w;
    float s2 = v.x * v.x + v.y * v.y + v.z * v.z + v.w * v.w;
#pragma unroll
    for (int off = 32; off > 0; off >>= 1) {
        s1 += __shfl_down(s1, off, 64);
        s2 += __shfl_down(s2, off, 64);
    }
    const int lane = t & 63, wid = t >> 6;
    if (lane == 0) { red[wid] = s1; red[4 + wid] = s2; }
    __syncthreads();
    s1 = red[0] + red[1] + red[2] + red[3];
    s2 = red[4] + red[5] + red[6] + red[7];
    const float mu  = s1 * (1.f / 1024.f);
    const float var = s2 * (1.f / 1024.f) - mu * mu;
    const float rs  = rsqrtf(var + 1e-5f);
    const float* w  = w1; const float* bb = b1;
    if (sel && (r & (Nseq - 1)) >= MTt) { w = w2; bb = b2; }
    const float4 wv = ((const float4*)w)[t];
    const float4 bv = ((const float4*)bb)[t];
    ushort4 o;
    o.x = f2bu((v.x - mu) * rs * wv.x + bv.x);
    o.y = f2bu((v.y - mu) * rs * wv.y + bv.y);
    o.z = f2bu((v.z - mu) * rs * wv.z + bv.z);
    o.w = f2bu((v.w - mu) * rs * wv.w + bv.w);
    ((ushort4*)(out + (size_t)r * Cdim))[t] = o;
}

// fused fp32->bf16 weight conversion: 6 segments in one launch.
// segment float4 counts: 786432, 262144, 4x1048576; total 5,242,880 = 20480*256.
__global__ __launch_bounds__(256)
void cvt6_kernel(const float* __restrict__ s0, const float* __restrict__ s1,
                 const float* __restrict__ s2, const float* __restrict__ s3,
                 const float* __restrict__ s4, const float* __restrict__ s5,
                 unsigned short* __restrict__ d0, unsigned short* __restrict__ d1,
                 unsigned short* __restrict__ d2, unsigned short* __restrict__ d3,
                 unsigned short* __restrict__ d4, unsigned short* __restrict__ d5)
{
    size_t i = (size_t)blockIdx.x * 256 + threadIdx.x;
    const float* s; unsigned short* d; size_t off;
    if      (i <  786432) { s = s0; d = d0; off = 0;       }
    else if (i < 1048576) { s = s1; d = d1; off = 786432;  }
    else if (i < 2097152) { s = s2; d = d2; off = 1048576; }
    else if (i < 3145728) { s = s3; d = d3; off = 2097152; }
    else if (i < 4194304) { s = s4; d = d4; off = 3145728; }
    else                  { s = s5; d = d5; off = 4194304; }
    size_t j = i - off;
    float4 v = ((const float4*)s)[j];
    ushort4 o;
    o.x = f2bu(v.x); o.y = f2bu(v.y); o.z = f2bu(v.z); o.w = f2bu(v.w);
    ((ushort4*)d)[j] = o;
}

// ---------------------------------------------------------------------------
extern "C" void kernel_launch(void* const* d_in, const int* in_sizes, int n_in,
                              void* d_out, int out_size, void* d_ws, size_t ws_size,
                              hipStream_t stream)
{
    const float* x    = (const float*)d_in[0];
    const int*   mask = (const int*)  d_in[1];
    const float* rpb  = (const float*)d_in[2];
    const float* n1w  = (const float*)d_in[3];
    const float* n1b  = (const float*)d_in[4];
    const float* qkvw = (const float*)d_in[5];
    const float* qb   = (const float*)d_in[6];
    const float* vb   = (const float*)d_in[7];
    const float* pw   = (const float*)d_in[8];
    const float* pb   = (const float*)d_in[9];
    const float* g1   = (const float*)d_in[10];
    const float* g2   = (const float*)d_in[11];
    const float* n2tw = (const float*)d_in[12];
    const float* n2tb = (const float*)d_in[13];
    const float* tf1w = (const float*)d_in[14];
    const float* tf1b = (const float*)d_in[15];
    const float* tf2w = (const float*)d_in[16];
    const float* tf2b = (const float*)d_in[17];
    const float* n2iw = (const float*)d_in[18];
    const float* n2ib = (const float*)d_in[19];
    const float* if1w = (const float*)d_in[20];
    const float* if1b = (const float*)d_in[21];
    const float* if2w = (const float*)d_in[22];
    const float* if2b = (const float*)d_in[23];
    float* out = (float*)d_out;

    char* ws = (char*)d_ws;
    unsigned short* h    = (unsigned short*)(ws);
    unsigned short* qbuf = (unsigned short*)(ws + 16777216);
    unsigned short* kbuf = (unsigned short*)(ws + 33554432);
    unsigned short* vtb  = (unsigned short*)(ws + 50331648);
    unsigned short* hid  = (unsigned short*)(ws);            // overlap (A dead by FC1)
    float*          x1   = (float*)(ws + 67108864);
    unsigned short* att  = (unsigned short*)(ws + 100663296);
    unsigned short* h2   = (unsigned short*)(ws + 100663296);// reuse (att dead by LN2)
    unsigned short* wqkv = (unsigned short*)(ws + 117440512);
    unsigned short* wprj = (unsigned short*)(ws + 123731968);
    unsigned short* wtf1 = (unsigned short*)(ws + 125829120);
    unsigned short* wtf2 = (unsigned short*)(ws + 134217728);
    unsigned short* wif1 = (unsigned short*)(ws + 142606336);
    unsigned short* wif2 = (unsigned short*)(ws + 150994944);

    // 1) weights fp32 -> bf16 (single fused launch)
    cvt6_kernel<<<dim3(20480), 256, 0, stream>>>(
        qkvw, pw, tf1w, tf2w, if1w, if2w,
        wqkv, wprj, wtf1, wtf2, wif1, wif2);

    // 2) LN1
    ln_kernel<<<dim3(8192), 256, 0, stream>>>(x, h, n1w, n1b, n1w, n1b, 0);

    // 3) QKV projection
    gemm128<0,0,0><<<dim3(24, 64), 256, 0, stream>>>(
        h, wqkv, 8192, 1024, qb, vb, nullptr, nullptr,
        nullptr, nullptr, qbuf, kbuf, vtb, 0);

    // 4) attention
    attn_kernel<<<dim3(1024), 256, 0, stream>>>(qbuf, kbuf, vtb, rpb, mask, att);

    // 5) output projection + gamma_1 residual -> x1 (fp32)
    gemm128<1,0,0><<<dim3(8, 64), 256, 0, stream>>>(
        att, wprj, 8192, 1024, pb, nullptr, g1, x,
        x1, nullptr, nullptr, nullptr, nullptr, 0);

    // 6) LN2
    ln_kernel<<<dim3(8192), 256, 0, stream>>>(x1, h2, n2tw, n2tb, n2iw, n2ib, 1);

    // 7) FC1 + gelu
    gemm128<2,1,0><<<dim3(32, 2), 256, 0, stream>>>(
        h2, wtf1, 160, 1024, tf1b, nullptr, nullptr, nullptr,
        nullptr, hid, nullptr, nullptr, nullptr, 0);
    gemm128<2,2,0><<<dim3(32, 63), 256, 0, stream>>>(
        h2, wif1, 8032, 1024, if1b, nullptr, nullptr, nullptr,
        nullptr, hid, nullptr, nullptr, nullptr, 160);

    // 8) FC2 + gamma_2 residual
    gemm128<3,0,1><<<dim3(8, 2), 256, 0, stream>>>(
        hid, wtf2, 160, 4096, tf2b, nullptr, g2, x1,
        out, nullptr, nullptr, nullptr, nullptr, 0);
    gemm128<3,0,2><<<dim3(8, 63), 256, 0, stream>>>(
        hid + (size_t)160 * HIDd, wif2, 8032, 4096, if2b, nullptr, g2, x1,
        out, nullptr, nullptr, nullptr, nullptr, 0);
}

// Round 7
// 1150.963 us; speedup vs baseline: 1.1138x; 1.1138x over previous
//
#include <hip/hip_runtime.h>
#include <hip/hip_bf16.h>
#include <math.h>

// Problem constants
#define Bsz  4
#define Nseq 2048
#define Cdim 1024
#define Hn   16
#define HDd  64
#define MTt  40
#define HIDd 4096

typedef __attribute__((ext_vector_type(8))) short  short8;
typedef __attribute__((ext_vector_type(4))) float  floatx4;

__device__ __forceinline__ floatx4 mfma16(short8 a, short8 b, floatx4 c) {
    return __builtin_amdgcn_mfma_f32_16x16x32_bf16(a, b, c, 0, 0, 0);
}

// async global->LDS, 16B per lane; LDS dest must be wave-uniform base + lane*16
__device__ __forceinline__ void load_lds16(const void* g, void* l) {
    __builtin_amdgcn_global_load_lds(
        (__attribute__((address_space(1))) void*)(g),
        (__attribute__((address_space(3))) void*)(l),
        16, 0, 0);
}

__device__ __forceinline__ unsigned short f2bu(float f) {
    union { __hip_bfloat16 h; unsigned short u; } cv;
    cv.h = __float2bfloat16(f);
    return cv.u;
}

template<int MAP>
__device__ __forceinline__ int rowmap(int r) {
    if constexpr (MAP == 1) {          // token rows: r in [0,160) -> b*N + n, n<MT
        int b = r / MTt; return b * Nseq + (r - b * MTt);
    } else if constexpr (MAP == 2) {   // image rows: r in [0,8032) -> b*N + MT + n
        int b = r / (Nseq - MTt); return b * Nseq + MTt + (r - b * (Nseq - MTt));
    } else {
        return r;
    }
}

// ---------------------------------------------------------------------------
// 128x128 tile GEMM, BK=64, C = A[M,K] * Bw[N,K]^T (+bias, epilogues)
// EPI: 0 = QKV scatter (q*scale, k, v^T)   1 = proj (+g1 residual, fp32 out)
//      2 = FC1 + exact gelu (bf16 out)     3 = FC2 (+g2 residual scatter, fp32)
// ---------------------------------------------------------------------------
template<int EPI, int AMAP, int CMAP>
__global__ __launch_bounds__(256, 3)
void gemm128(const unsigned short* __restrict__ A,
             const unsigned short* __restrict__ Bw,
             int M, int K,
             const float* __restrict__ bias,
             const float* __restrict__ bias2,
             const float* __restrict__ gamma,
             const float* __restrict__ resid,
             float* __restrict__ outf,
             unsigned short* __restrict__ outh,
             unsigned short* __restrict__ q_out,
             unsigned short* __restrict__ k_out,
             unsigned short* __restrict__ vt_out,
             int out_row_off)
{
    __shared__ unsigned short As[128 * 64];
    __shared__ unsigned short Bs[128 * 64];

    const int t    = threadIdx.x;
    const int lane = t & 63;
    const int quad = lane >> 4, lcol = lane & 15;
    const int wid  = t >> 6;
    const int wm   = wid >> 1, wn = wid & 1;
    const int m0   = blockIdx.y * 128;
    const int n0   = blockIdx.x * 128;

    floatx4 zero4 = {0.f, 0.f, 0.f, 0.f};
    floatx4 acc[4][4];
#pragma unroll
    for (int i = 0; i < 4; ++i)
#pragma unroll
        for (int j = 0; j < 4; ++j) acc[i][j] = zero4;

    const int c8 = (t & 7) << 3;            // element col within 64-wide K slab
    const unsigned short* aga[4];
    const unsigned short* bga[4];
#pragma unroll
    for (int i = 0; i < 4; ++i) {
        int lr = m0 + i * 32 + (t >> 3);
        if (lr > M - 1) lr = M - 1;
        int sr = rowmap<AMAP>(lr);
        aga[i] = A  + (size_t)sr * K + c8;
        bga[i] = Bw + (size_t)(n0 + i * 32 + (t >> 3)) * K + c8;
    }

    const int nkt = K >> 6;
    for (int kt = 0; kt < nkt; ++kt) {
        const int k0 = kt << 6;
        __syncthreads();
#pragma unroll
        for (int i = 0; i < 4; ++i)
            load_lds16(aga[i] + k0, (unsigned short*)As + i * 2048 + t * 8);
#pragma unroll
        for (int i = 0; i < 4; ++i)
            load_lds16(bga[i] + k0, (unsigned short*)Bs + i * 2048 + t * 8);
        __syncthreads();

#pragma unroll
        for (int kk = 0; kk < 2; ++kk) {
            short8 af[4], bfr[4];
#pragma unroll
            for (int i = 0; i < 4; ++i)
                af[i] = *(const short8*)(As + (wm * 64 + i * 16 + lcol) * 64 + kk * 32 + quad * 8);
#pragma unroll
            for (int j = 0; j < 4; ++j)
                bfr[j] = *(const short8*)(Bs + (wn * 64 + j * 16 + lcol) * 64 + kk * 32 + quad * 8);
#pragma unroll
            for (int i = 0; i < 4; ++i)
#pragma unroll
                for (int j = 0; j < 4; ++j)
                    acc[i][j] = mfma16(af[i], bfr[j], acc[i][j]);
        }
    }

    // epilogue; C/D layout: col = lane&15, row = quad*4 + reg  [m89-verified]
    const int rb = m0 + wm * 64 + quad * 4;
    const int cb = n0 + wn * 64 + lcol;
#pragma unroll
    for (int i = 0; i < 4; ++i) {
#pragma unroll
        for (int j = 0; j < 4; ++j) {
            const int c = cb + j * 16;
#pragma unroll
            for (int rg = 0; rg < 4; ++rg) {
                const int r = rb + i * 16 + rg;
                if (r >= M) continue;
                float v = acc[i][j][rg];
                if constexpr (EPI == 0) {
                    int b = r >> 11, n = r & (Nseq - 1);
                    if (c < Cdim) {
                        float qv = (v + bias[c]) * 0.125f;    // (h@W^T + q_bias)*scale
                        int hh = c >> 6, d = c & 63;
                        q_out[(((size_t)b * Hn + hh) * Nseq + n) * HDd + d] = f2bu(qv);
                    } else if (c < 2 * Cdim) {
                        int cc = c - Cdim; int hh = cc >> 6, d = cc & 63;
                        k_out[(((size_t)b * Hn + hh) * Nseq + n) * HDd + d] = f2bu(v);
                    } else {
                        int cc = c - 2 * Cdim; int hh = cc >> 6, d = cc & 63;
                        vt_out[(((size_t)b * Hn + hh) * HDd + d) * Nseq + n] = f2bu(v + bias2[cc]);
                    }
                } else if constexpr (EPI == 1) {
                    size_t idx = (size_t)r * Cdim + c;
                    outf[idx] = resid[idx] + gamma[c] * (v + bias[c]);
                } else if constexpr (EPI == 2) {
                    float xg = v + bias[c];
                    float ge = 0.5f * xg * (1.f + erff(xg * 0.70710678118654752f));
                    outh[(size_t)(r + out_row_off) * HIDd + c] = f2bu(ge);
                } else {
                    int sr = rowmap<CMAP>(r);
                    size_t idx = (size_t)sr * Cdim + c;
                    outf[idx] = resid[idx] + gamma[c] * (v + bias[c]);
                }
            }
        }
    }
}

// ---------------------------------------------------------------------------
// Flash attention v7: r5 config (229 us) + XCD swizzle ONLY (occupancy 3/CU).
//  - FETCH_SIZE is TCC(=per-XCD L2) miss bytes. b-siblings of one (h,qt)
//    read the same 1MB bias tile; default dispatch round-robins them onto
//    4 different XCDs -> each XCD's L2 fetches the tile separately (~2x
//    after L3). Swizzle wg=(bid&7)*128+(bid>>3): XCD k owns contiguous
//    wg in [128k,128k+128) -> siblings co-XCD + kt-lockstep; per-kt live
//    bias slice/XCD ~3 MB <= 4 MB L2. r4's failure was the bundled 4/CU
//    occupancy (live set 2x -> L2/L3 thrash), not the swizzle.
//  - NO nt on bias (r6: fetch unchanged, BW halved -> reverted).
//  - Bias loaded directly in MFMA C-layout into registers; no EB region.
//  - Ps/Vs stride-72; V register-staged (DMA can't pad - m104/m108).
//  - No max subtraction (scores bounded); row sums via MFMA ones-column.
//  - Ps aliases Qs (Q frags in regs; lgkm drained at first barrier).
// LDS: Ps 128x72 (>=Qs 128x64) | Ks 64x64 | Vs 64x72 = 35,840 B
// grid: 1024 blocks; block 256 = 4 waves x 32 q-rows.
// ---------------------------------------------------------------------------
__global__ __launch_bounds__(256, 3)
void attn_kernel(const unsigned short* __restrict__ q,
                 const unsigned short* __restrict__ k,
                 const unsigned short* __restrict__ vt,
                 const float* __restrict__ bias,
                 const int* __restrict__ mask,
                 unsigned short* __restrict__ attn_o)
{
    __shared__ unsigned short lds[17920];
    unsigned short* PS = lds;            // 128 x 72   [0, 9216)   (Qs 128x64 alias)
    unsigned short* KS = lds + 9216;     // 64 keys x 64d [9216, 13312)
    unsigned short* VS = lds + 13312;    // 64 d x 72  [13312, 17920)

    const int t    = threadIdx.x;
    const int lane = t & 63, wid = t >> 6;
    const int quad = lane >> 4, lcol = lane & 15;

    // XCD-aware swizzle (bijective: 1024 = 8 XCDs x 128); occupancy kept 3/CU
    const int bid = blockIdx.x;
    const int wg  = (bid & 7) * 128 + (bid >> 3);

    const int b  = wg & 3;
    const int hq = wg >> 2;
    const int h  = hq & 15;
    const int qt = hq >> 4;

    const size_t bh = (size_t)b * Hn + h;
    const unsigned short* qbase = q  + (bh * Nseq + qt * 128) * HDd;
    const unsigned short* kbase = k  + bh * Nseq * HDd;
    const unsigned short* vbase = vt + bh * HDd * Nseq;
    const float* bbase = bias + ((size_t)h * Nseq + qt * 128) * Nseq;

    // Q -> LDS (PS region, stride 64), read frags, then PS is reusable
#pragma unroll
    for (int i = 0; i < 4; ++i)
        load_lds16(qbase + i * 2048 + t * 8, (unsigned short*)PS + i * 2048 + t * 8);
    __syncthreads();

    short8 aq[2][2];
#pragma unroll
    for (int mt = 0; mt < 2; ++mt)
#pragma unroll
        for (int kk = 0; kk < 2; ++kk)
            aq[mt][kk] = *(const short8*)(PS + (wid * 32 + mt * 16 + lcol) * 64 + kk * 32 + quad * 8);

    short8 ones8;
#pragma unroll
    for (int i = 0; i < 8; ++i) ones8[i] = (short)0x3F80;   // bf16 1.0

    floatx4 zero4 = {0.f, 0.f, 0.f, 0.f};
    floatx4 o[2][4], osum[2];
#pragma unroll
    for (int mt = 0; mt < 2; ++mt) {
        osum[mt] = zero4;
#pragma unroll
        for (int dj = 0; dj < 4; ++dj) o[mt][dj] = zero4;
    }

    const int tr = t >> 3;            // 0..31
    const int tc = (t & 7) << 3;      // 0..56

    for (int kt = 0; kt < 32; ++kt) {
        __syncthreads();   // prev tile's PS/VS consumers done; frag lgkm drained (kt=0)

        // ---- staging: issue all global reads first ----
        const unsigned short* kb = kbase + kt * 4096;
        load_lds16(kb + t * 8,        KS + t * 8);
        load_lds16(kb + 2048 + t * 8, KS + 2048 + t * 8);

        short8 vreg[2];
#pragma unroll
        for (int i = 0; i < 2; ++i)
            vreg[i] = *(const short8*)(vbase + (size_t)(i * 32 + tr) * Nseq + kt * 64 + tc);

        // bias directly in MFMA C-layout: row = wid*32+mt*16+quad*4+rg,
        // col = kt*64 + j*16 + lcol  (lanes 0..15 -> 16 consecutive floats)
        float breg[2][4][4];
#pragma unroll
        for (int mt = 0; mt < 2; ++mt)
#pragma unroll
            for (int rg = 0; rg < 4; ++rg) {
                const float* bp = bbase
                    + (size_t)(wid * 32 + mt * 16 + quad * 4 + rg) * Nseq
                    + kt * 64;
#pragma unroll
                for (int j = 0; j < 4; ++j)
                    breg[mt][rg][j] = bp[j * 16 + lcol];
            }

        int mk[4];
#pragma unroll
        for (int j = 0; j < 4; ++j)
            mk[j] = mask[b * Nseq + kt * 64 + j * 16 + lcol];

        // ---- LDS writes (padded stride 72) ----
#pragma unroll
        for (int i = 0; i < 2; ++i)
            *(short8*)(VS + (i * 32 + tr) * 72 + tc) = vreg[i];
        __syncthreads();   // K DMA + V lds writes visible

        // ---- S = Q K^T ----
        floatx4 s[2][4];
#pragma unroll
        for (int mt = 0; mt < 2; ++mt)
#pragma unroll
            for (int j = 0; j < 4; ++j) s[mt][j] = zero4;
#pragma unroll
        for (int kk = 0; kk < 2; ++kk) {
#pragma unroll
            for (int j = 0; j < 4; ++j) {
                short8 bk = *(const short8*)(KS + (j * 16 + lcol) * 64 + kk * 32 + quad * 8);
                s[0][j] = mfma16(aq[0][kk], bk, s[0][j]);
                s[1][j] = mfma16(aq[1][kk], bk, s[1][j]);
            }
        }

        // ---- softmax numerators (exp(s+bias), masked), write P (C-layout rows) ----
#pragma unroll
        for (int mt = 0; mt < 2; ++mt) {
#pragma unroll
            for (int rg = 0; rg < 4; ++rg) {
                const int prow = wid * 32 + mt * 16 + quad * 4 + rg;
#pragma unroll
                for (int j = 0; j < 4; ++j) {
                    float p = __expf(s[mt][j][rg] + breg[mt][rg][j]);
                    p = mk[j] ? p : 0.f;
                    PS[prow * 72 + j * 16 + lcol] = f2bu(p);
                }
            }
        }

        // ---- O += P V  (+ row-sum via ones column); own-wave rows, no barrier ----
#pragma unroll
        for (int kk2 = 0; kk2 < 2; ++kk2) {
            short8 ap[2], bv[4];
#pragma unroll
            for (int mt = 0; mt < 2; ++mt)
                ap[mt] = *(const short8*)(PS + (wid * 32 + mt * 16 + lcol) * 72 + kk2 * 32 + quad * 8);
#pragma unroll
            for (int dj = 0; dj < 4; ++dj)
                bv[dj] = *(const short8*)(VS + (dj * 16 + lcol) * 72 + kk2 * 32 + quad * 8);
#pragma unroll
            for (int mt = 0; mt < 2; ++mt) {
#pragma unroll
                for (int dj = 0; dj < 4; ++dj)
                    o[mt][dj] = mfma16(ap[mt], bv[dj], o[mt][dj]);
                osum[mt] = mfma16(ap[mt], ones8, osum[mt]);
            }
        }
    }

    // ---- normalize by MFMA row sums, store ----
#pragma unroll
    for (int mt = 0; mt < 2; ++mt) {
#pragma unroll
        for (int rg = 0; rg < 4; ++rg) {
            const float inv = 1.f / osum[mt][rg];
            const int rq = qt * 128 + wid * 32 + mt * 16 + quad * 4 + rg;
#pragma unroll
            for (int dj = 0; dj < 4; ++dj) {
                const int c = h * HDd + dj * 16 + lcol;
                attn_o[((size_t)b * Nseq + rq) * Cdim + c] = f2bu(o[mt][dj][rg] * inv);
            }
        }
    }
}

// ---------------------------------------------------------------------------
// LayerNorm over C=1024, one block per token. sel=1: pick (w1,b1) if n<MT else (w2,b2)
// ---------------------------------------------------------------------------
__global__ __launch_bounds__(256)
void ln_kernel(const float* __restrict__ x,
               unsigned short* __restrict__ out,
               const float* __restrict__ w1, const float* __restrict__ b1,
               const float* __restrict__ w2, const float* __restrict__ b2,
               int sel)
{
    __shared__ float red[8];
    const int r = blockIdx.x, t = threadIdx.x;
    const float4 v = ((const float4*)(x + (size_t)r * Cdim))[t];
    float s1 = v.x + v.y + v.z + v.w;
    float s2 = v.x * v.x + v.y * v.y + v.z * v.z + v.w * v.w;
#pragma unroll
    for (int off = 32; off > 0; off >>= 1) {
        s1 += __shfl_down(s1, off, 64);
        s2 += __shfl_down(s2, off, 64);
    }
    const int lane = t & 63, wid = t >> 6;
    if (lane == 0) { red[wid] = s1; red[4 + wid] = s2; }
    __syncthreads();
    s1 = red[0] + red[1] + red[2] + red[3];
    s2 = red[4] + red[5] + red[6] + red[7];
    const float mu  = s1 * (1.f / 1024.f);
    const float var = s2 * (1.f / 1024.f) - mu * mu;
    const float rs  = rsqrtf(var + 1e-5f);
    const float* w  = w1; const float* bb = b1;
    if (sel && (r & (Nseq - 1)) >= MTt) { w = w2; bb = b2; }
    const float4 wv = ((const float4*)w)[t];
    const float4 bv = ((const float4*)bb)[t];
    ushort4 o;
    o.x = f2bu((v.x - mu) * rs * wv.x + bv.x);
    o.y = f2bu((v.y - mu) * rs * wv.y + bv.y);
    o.z = f2bu((v.z - mu) * rs * wv.z + bv.z);
    o.w = f2bu((v.w - mu) * rs * wv.w + bv.w);
    ((ushort4*)(out + (size_t)r * Cdim))[t] = o;
}

// fused fp32->bf16 weight conversion: 6 segments in one launch.
// segment float4 counts: 786432, 262144, 4x1048576; total 5,242,880 = 20480*256.
__global__ __launch_bounds__(256)
void cvt6_kernel(const float* __restrict__ s0, const float* __restrict__ s1,
                 const float* __restrict__ s2, const float* __restrict__ s3,
                 const float* __restrict__ s4, const float* __restrict__ s5,
                 unsigned short* __restrict__ d0, unsigned short* __restrict__ d1,
                 unsigned short* __restrict__ d2, unsigned short* __restrict__ d3,
                 unsigned short* __restrict__ d4, unsigned short* __restrict__ d5)
{
    size_t i = (size_t)blockIdx.x * 256 + threadIdx.x;
    const float* s; unsigned short* d; size_t off;
    if      (i <  786432) { s = s0; d = d0; off = 0;       }
    else if (i < 1048576) { s = s1; d = d1; off = 786432;  }
    else if (i < 2097152) { s = s2; d = d2; off = 1048576; }
    else if (i < 3145728) { s = s3; d = d3; off = 2097152; }
    else if (i < 4194304) { s = s4; d = d4; off = 3145728; }
    else                  { s = s5; d = d5; off = 4194304; }
    size_t j = i - off;
    float4 v = ((const float4*)s)[j];
    ushort4 o;
    o.x = f2bu(v.x); o.y = f2bu(v.y); o.z = f2bu(v.z); o.w = f2bu(v.w);
    ((ushort4*)d)[j] = o;
}

// ---------------------------------------------------------------------------
extern "C" void kernel_launch(void* const* d_in, const int* in_sizes, int n_in,
                              void* d_out, int out_size, void* d_ws, size_t ws_size,
                              hipStream_t stream)
{
    const float* x    = (const float*)d_in[0];
    const int*   mask = (const int*)  d_in[1];
    const float* rpb  = (const float*)d_in[2];
    const float* n1w  = (const float*)d_in[3];
    const float* n1b  = (const float*)d_in[4];
    const float* qkvw = (const float*)d_in[5];
    const float* qb   = (const float*)d_in[6];
    const float* vb   = (const float*)d_in[7];
    const float* pw   = (const float*)d_in[8];
    const float* pb   = (const float*)d_in[9];
    const float* g1   = (const float*)d_in[10];
    const float* g2   = (const float*)d_in[11];
    const float* n2tw = (const float*)d_in[12];
    const float* n2tb = (const float*)d_in[13];
    const float* tf1w = (const float*)d_in[14];
    const float* tf1b = (const float*)d_in[15];
    const float* tf2w = (const float*)d_in[16];
    const float* tf2b = (const float*)d_in[17];
    const float* n2iw = (const float*)d_in[18];
    const float* n2ib = (const float*)d_in[19];
    const float* if1w = (const float*)d_in[20];
    const float* if1b = (const float*)d_in[21];
    const float* if2w = (const float*)d_in[22];
    const float* if2b = (const float*)d_in[23];
    float* out = (float*)d_out;

    char* ws = (char*)d_ws;
    unsigned short* h    = (unsigned short*)(ws);
    unsigned short* qbuf = (unsigned short*)(ws + 16777216);
    unsigned short* kbuf = (unsigned short*)(ws + 33554432);
    unsigned short* vtb  = (unsigned short*)(ws + 50331648);
    unsigned short* hid  = (unsigned short*)(ws);            // overlap (A dead by FC1)
    float*          x1   = (float*)(ws + 67108864);
    unsigned short* att  = (unsigned short*)(ws + 100663296);
    unsigned short* h2   = (unsigned short*)(ws + 100663296);// reuse (att dead by LN2)
    unsigned short* wqkv = (unsigned short*)(ws + 117440512);
    unsigned short* wprj = (unsigned short*)(ws + 123731968);
    unsigned short* wtf1 = (unsigned short*)(ws + 125829120);
    unsigned short* wtf2 = (unsigned short*)(ws + 134217728);
    unsigned short* wif1 = (unsigned short*)(ws + 142606336);
    unsigned short* wif2 = (unsigned short*)(ws + 150994944);

    // 1) weights fp32 -> bf16 (single fused launch)
    cvt6_kernel<<<dim3(20480), 256, 0, stream>>>(
        qkvw, pw, tf1w, tf2w, if1w, if2w,
        wqkv, wprj, wtf1, wtf2, wif1, wif2);

    // 2) LN1
    ln_kernel<<<dim3(8192), 256, 0, stream>>>(x, h, n1w, n1b, n1w, n1b, 0);

    // 3) QKV projection
    gemm128<0,0,0><<<dim3(24, 64), 256, 0, stream>>>(
        h, wqkv, 8192, 1024, qb, vb, nullptr, nullptr,
        nullptr, nullptr, qbuf, kbuf, vtb, 0);

    // 4) attention
    attn_kernel<<<dim3(1024), 256, 0, stream>>>(qbuf, kbuf, vtb, rpb, mask, att);

    // 5) output projection + gamma_1 residual -> x1 (fp32)
    gemm128<1,0,0><<<dim3(8, 64), 256, 0, stream>>>(
        att, wprj, 8192, 1024, pb, nullptr, g1, x,
        x1, nullptr, nullptr, nullptr, nullptr, 0);

    // 6) LN2
    ln_kernel<<<dim3(8192), 256, 0, stream>>>(x1, h2, n2tw, n2tb, n2iw, n2ib, 1);

    // 7) FC1 + gelu
    gemm128<2,1,0><<<dim3(32, 2), 256, 0, stream>>>(
        h2, wtf1, 160, 1024, tf1b, nullptr, nullptr, nullptr,
        nullptr, hid, nullptr, nullptr, nullptr, 0);
    gemm128<2,2,0><<<dim3(32, 63), 256, 0, stream>>>(
        h2, wif1, 8032, 1024, if1b, nullptr, nullptr, nullptr,
        nullptr, hid, nullptr, nullptr, nullptr, 160);

    // 8) FC2 + gamma_2 residual
    gemm128<3,0,1><<<dim3(8, 2), 256, 0, stream>>>(
        hid, wtf2, 160, 4096, tf2b, nullptr, g2, x1,
        out, nullptr, nullptr, nullptr, nullptr, 0);
    gemm128<3,0,2><<<dim3(8, 63), 256, 0, stream>>>(
        hid + (size_t)160 * HIDd, wif2, 8032, 4096, if2b, nullptr, g2, x1,
        out, nullptr, nullptr, nullptr, nullptr, 0);
}